// Round 1
// baseline (550.091 us; speedup 1.0000x reference)
//
#include <hip/hip_runtime.h>

constexpr int H  = 128;     // hidden dim
constexpr int T  = 8;       // edge types
constexpr int H4 = H / 4;   // float4 per row

__device__ __forceinline__ float4 relu_add(float4 a, float4 c) {
    float4 h;
    h.x = fmaxf(a.x + c.x, 0.f);
    h.y = fmaxf(a.y + c.y, 0.f);
    h.z = fmaxf(a.z + c.z, 0.f);
    h.w = fmaxf(a.w + c.w, 0.f);
    return h;
}

// 8 lanes per edge; each lane owns 16 features (4x float4, strided so each
// load instruction reads a contiguous 128B chunk per edge-row). Two edges
// per thread per iteration to amortize LDS W reads and boost load MLP.
__global__ __launch_bounds__(256, 4)
void edge_type_kernel(const float* __restrict__ x,
                      const int* __restrict__ eidx,
                      const float* __restrict__ W,
                      const float* __restrict__ b,
                      float* __restrict__ out,
                      int E)
{
    __shared__ float sW[T * H];   // 4 KB
    for (int i = threadIdx.x; i < T * H; i += blockDim.x) sW[i] = W[i];
    __syncthreads();
    const float4* sW4 = reinterpret_cast<const float4*>(sW);

    const int lane    = threadIdx.x & 7;
    const int group   = (blockIdx.x * blockDim.x + threadIdx.x) >> 3;
    const int ngroups = (gridDim.x * blockDim.x) >> 3;
    const float bias  = b[lane];

    for (int e0 = group; e0 < E; e0 += 2 * ngroups) {
        const int  e1   = e0 + ngroups;       // second edge (may be >= E)
        const bool has1 = e1 < E;
        const int  e1c  = has1 ? e1 : e0;     // clamp for safe loads

        const int s0 = eidx[e0];
        const int d0 = eidx[E + e0];
        const int s1 = eidx[e1c];
        const int d1 = eidx[E + e1c];

        const float4* xs0 = reinterpret_cast<const float4*>(x) + (size_t)s0 * H4;
        const float4* xd0 = reinterpret_cast<const float4*>(x) + (size_t)d0 * H4;
        const float4* xs1 = reinterpret_cast<const float4*>(x) + (size_t)s1 * H4;
        const float4* xd1 = reinterpret_cast<const float4*>(x) + (size_t)d1 * H4;

        float4 h0[4], h1[4];
        #pragma unroll
        for (int j = 0; j < 4; ++j) {
            const int o = j * 8 + lane;       // lanes 0..7 -> contiguous 128B
            float4 a0 = xs0[o], c0 = xd0[o];
            float4 a1 = xs1[o], c1 = xd1[o];
            h0[j] = relu_add(a0, c0);
            h1[j] = relu_add(a1, c1);
        }

        float p0[T], p1[T];
        #pragma unroll
        for (int t = 0; t < T; ++t) { p0[t] = 0.f; p1[t] = 0.f; }

        #pragma unroll
        for (int t = 0; t < T; ++t) {
            #pragma unroll
            for (int j = 0; j < 4; ++j) {
                float4 w = sW4[t * H4 + j * 8 + lane];  // broadcast across 8 groups
                p0[t] = fmaf(h0[j].x, w.x, p0[t]);
                p0[t] = fmaf(h0[j].y, w.y, p0[t]);
                p0[t] = fmaf(h0[j].z, w.z, p0[t]);
                p0[t] = fmaf(h0[j].w, w.w, p0[t]);
                p1[t] = fmaf(h1[j].x, w.x, p1[t]);
                p1[t] = fmaf(h1[j].y, w.y, p1[t]);
                p1[t] = fmaf(h1[j].z, w.z, p1[t]);
                p1[t] = fmaf(h1[j].w, w.w, p1[t]);
            }
        }

        // butterfly reduce across the 8-lane group (xor 1,2,4 stays in-group)
        #pragma unroll
        for (int s = 1; s < 8; s <<= 1) {
            #pragma unroll
            for (int t = 0; t < T; ++t) {
                p0[t] += __shfl_xor(p0[t], s);
                p1[t] += __shfl_xor(p1[t], s);
            }
        }

        // lane l stores type l -> 64 lanes write 256B contiguous per instr
        float r0 = p0[0], r1 = p1[0];
        #pragma unroll
        for (int t = 1; t < T; ++t) {
            r0 = (lane == t) ? p0[t] : r0;
            r1 = (lane == t) ? p1[t] : r1;
        }
        out[(size_t)e0 * T + lane] = r0 + bias;
        if (has1) out[(size_t)e1 * T + lane] = r1 + bias;
    }
}

extern "C" void kernel_launch(void* const* d_in, const int* in_sizes, int n_in,
                              void* d_out, int out_size, void* d_ws, size_t ws_size,
                              hipStream_t stream) {
    const float* x    = (const float*)d_in[0];   // [N_NODES, 128] fp32
    const int*   eidx = (const int*)d_in[1];     // [2, E] int32 (harness convention)
    const float* W    = (const float*)d_in[2];   // [8, 128] fp32
    const float* b    = (const float*)d_in[3];   // [8] fp32
    float*       out  = (float*)d_out;           // [E, 8] fp32

    const int E = in_sizes[1] / 2;               // edge_index is [2, E]
    edge_type_kernel<<<dim3(2048), dim3(256), 0, stream>>>(x, eidx, W, b, out, E);
}

// Round 2
// 162.872 us; speedup vs baseline: 3.3774x; 3.3774x over previous
//
#include <hip/hip_runtime.h>

constexpr int H  = 128;     // hidden dim
constexpr int T  = 8;       // edge types
constexpr int H4 = H / 4;   // float4 per row

__device__ __forceinline__ float4 relu_add(float4 a, float4 c) {
    float4 h;
    h.x = fmaxf(a.x + c.x, 0.f);
    h.y = fmaxf(a.y + c.y, 0.f);
    h.z = fmaxf(a.z + c.z, 0.f);
    h.w = fmaxf(a.w + c.w, 0.f);
    return h;
}

// One edge per 8-lane group, exact grid (no loop). Each lane owns 16 of 128
// features as 4x float4 strided so each load instruction covers a contiguous
// 128B row chunk per edge. Gather chunks are fused straight into the FMAs so
// no h[] array stays live (round-1 spilled ~200B/thread to scratch: WRITE_SIZE
// was 535MB vs 19MB logical). 7-shfl merge tree lands type t's sum on lane t.
__global__ __launch_bounds__(256, 4)
void edge_type_kernel(const float* __restrict__ x,
                      const int* __restrict__ eidx,
                      const float* __restrict__ W,
                      const float* __restrict__ b,
                      float* __restrict__ out,
                      int E)
{
    __shared__ float sW[T * H];   // 4 KB
    for (int i = threadIdx.x; i < T * H; i += blockDim.x) sW[i] = W[i];
    __syncthreads();
    const float4* sW4 = reinterpret_cast<const float4*>(sW);

    const int lane = threadIdx.x & 7;
    const int e    = (blockIdx.x * blockDim.x + threadIdx.x) >> 3;
    if (e >= E) return;

    const int s = eidx[e];
    const int d = eidx[E + e];
    const float4* xs = reinterpret_cast<const float4*>(x) + (size_t)s * H4;
    const float4* xd = reinterpret_cast<const float4*>(x) + (size_t)d * H4;

    float p[T];
    #pragma unroll
    for (int t = 0; t < T; ++t) p[t] = 0.f;

    #pragma unroll
    for (int j = 0; j < 4; ++j) {
        const int o = j * 8 + lane;           // 8 lanes -> contiguous 128B
        float4 a = xs[o];
        float4 c = xd[o];
        float4 h = relu_add(a, c);
        #pragma unroll
        for (int t = 0; t < T; ++t) {
            float4 w = sW4[t * H4 + o];       // broadcast across 8 groups
            p[t] = fmaf(h.x, w.x,
                   fmaf(h.y, w.y,
                   fmaf(h.z, w.z,
                   fmaf(h.w, w.w, p[t]))));
        }
    }

    // Merge tree across the 8-lane group: 7 shfls total, lane l ends with the
    // full sum for type t == l (t = bit2*4 + bit1*2 + bit0 of lane).
    float q[4];
    #pragma unroll
    for (int k = 0; k < 4; ++k) {
        float keep = (lane & 1) ? p[2 * k + 1] : p[2 * k];
        float send = (lane & 1) ? p[2 * k]     : p[2 * k + 1];
        q[k] = keep + __shfl_xor(send, 1);
    }
    float r2[2];
    #pragma unroll
    for (int k = 0; k < 2; ++k) {
        float keep = (lane & 2) ? q[2 * k + 1] : q[2 * k];
        float send = (lane & 2) ? q[2 * k]     : q[2 * k + 1];
        r2[k] = keep + __shfl_xor(send, 2);
    }
    {
        float keep = (lane & 4) ? r2[1] : r2[0];
        float send = (lane & 4) ? r2[0] : r2[1];
        float r = keep + __shfl_xor(send, 4) + b[lane];
        // 64 lanes -> 256B contiguous; nontemporal: don't displace x in L2
        __builtin_nontemporal_store(r, &out[(size_t)e * T + lane]);
    }
}

extern "C" void kernel_launch(void* const* d_in, const int* in_sizes, int n_in,
                              void* d_out, int out_size, void* d_ws, size_t ws_size,
                              hipStream_t stream) {
    const float* x    = (const float*)d_in[0];   // [N_NODES, 128] fp32
    const int*   eidx = (const int*)d_in[1];     // [2, E] int32
    const float* W    = (const float*)d_in[2];   // [8, 128] fp32
    const float* b    = (const float*)d_in[3];   // [8] fp32
    float*       out  = (float*)d_out;           // [E, 8] fp32

    const int E = in_sizes[1] / 2;               // edge_index is [2, E]
    const int groups_per_block = 256 / 8;        // 32 edges per block
    const int blocks = (E + groups_per_block - 1) / groups_per_block;  // 18750
    edge_type_kernel<<<dim3(blocks), dim3(256), 0, stream>>>(x, eidx, W, b, out, E);
}

// Round 3
// 136.283 us; speedup vs baseline: 4.0364x; 1.1951x over previous
//
#include <hip/hip_runtime.h>

typedef _Float16 half2_t __attribute__((ext_vector_type(2)));

constexpr int H  = 128;     // hidden dim
constexpr int T  = 8;       // edge types
constexpr int H4 = H / 4;   // float4 per fp32 row

__device__ __forceinline__ float dot2acc(half2_t a, half2_t b, float c) {
#if __has_builtin(__builtin_amdgcn_fdot2)
    return __builtin_amdgcn_fdot2(a, b, c, false);
#else
    return fmaf((float)a.x, (float)b.x, fmaf((float)a.y, (float)b.y, c));
#endif
}

__device__ __forceinline__ half2_t hrelu_add(half2_t a, half2_t b) {
    half2_t s = a + b;
    half2_t r;
    r.x = s.x > (_Float16)0 ? s.x : (_Float16)0;
    r.y = s.y > (_Float16)0 ? s.y : (_Float16)0;
    return r;
}

__device__ __forceinline__ float f4_get(const float4& v, int k) {
    // k is a compile-time constant under full unroll
    return k == 0 ? v.x : k == 1 ? v.y : k == 2 ? v.z : v.w;
}

// ---------------- pre-pass: x fp32 -> fp16 into workspace ----------------
__global__ __launch_bounds__(256)
void cvt_x_kernel(const float4* __restrict__ x4, float4* __restrict__ o4, int n8) {
    int i = blockIdx.x * blockDim.x + threadIdx.x;
    if (i >= n8) return;
    float4 p = x4[2 * i], q = x4[2 * i + 1];
    half2_t a = {(_Float16)p.x, (_Float16)p.y};
    half2_t b = {(_Float16)p.z, (_Float16)p.w};
    half2_t c = {(_Float16)q.x, (_Float16)q.y};
    half2_t d = {(_Float16)q.z, (_Float16)q.w};
    float4 o;
    o.x = __builtin_bit_cast(float, a);
    o.y = __builtin_bit_cast(float, b);
    o.z = __builtin_bit_cast(float, c);
    o.w = __builtin_bit_cast(float, d);
    o4[i] = o;
}

// ---------------- main: fp16 gather, 2 edges per 8-lane group ----------------
// Row = 256B (128 x fp16). Lane owns 16 features as 2 x 16B chunks; per
// instruction 8 lanes cover a contiguous 128B half-row. Two edges per group
// share each W LDS read (halves LDS traffic) and double loads in flight
// (round-2 was miss-path latency-bound: 285MB at 3.4TB/s with ~12.8KB/CU in
// flight vs ~7KB needed). dot2 (v_dot2_f32_f16, fp32 accum) halves VALU fmas.
__global__ __launch_bounds__(256, 4)
void edge_type_fp16_kernel(const float4* __restrict__ xh,
                           const int* __restrict__ eidx,
                           const float* __restrict__ W,
                           const float* __restrict__ b,
                           float* __restrict__ out,
                           int E)
{
    __shared__ half2_t sW[T * H / 2];   // 2 KB, layout [t][f] fp16
    for (int i = threadIdx.x; i < T * H / 2; i += blockDim.x) {
        half2_t v;
        v.x = (_Float16)W[2 * i];
        v.y = (_Float16)W[2 * i + 1];
        sW[i] = v;
    }
    __syncthreads();
    const float4* sW4 = reinterpret_cast<const float4*>(sW);  // [t*16 + j*8 + lane]

    const int lane = threadIdx.x & 7;
    const int g    = threadIdx.x >> 3;            // 0..31
    const int base = blockIdx.x * 64;
    const int e0   = base + g;                    // wave's 8 groups -> 8 consecutive edges
    const int e1   = base + 32 + g;
    const bool v0  = e0 < E, v1 = e1 < E;
    const int e0c  = v0 ? e0 : 0, e1c = v1 ? e1 : 0;

    const int s0 = eidx[e0c], d0 = eidx[E + e0c];
    const int s1 = eidx[e1c], d1 = eidx[E + e1c];

    const float4* xs0 = xh + (size_t)s0 * 16;     // 16 float4 per fp16 row
    const float4* xd0 = xh + (size_t)d0 * 16;
    const float4* xs1 = xh + (size_t)s1 * 16;
    const float4* xd1 = xh + (size_t)d1 * 16;

    half2_t h0[8], h1[8];                         // 16 fp16 features per edge
    #pragma unroll
    for (int j = 0; j < 2; ++j) {
        const int o = j * 8 + lane;               // contiguous 128B per instr
        float4 a0 = xs0[o], c0 = xd0[o];
        float4 a1 = xs1[o], c1 = xd1[o];
        #pragma unroll
        for (int k = 0; k < 4; ++k) {
            h0[j * 4 + k] = hrelu_add(__builtin_bit_cast(half2_t, f4_get(a0, k)),
                                      __builtin_bit_cast(half2_t, f4_get(c0, k)));
            h1[j * 4 + k] = hrelu_add(__builtin_bit_cast(half2_t, f4_get(a1, k)),
                                      __builtin_bit_cast(half2_t, f4_get(c1, k)));
        }
    }

    float p0[T], p1[T];
    #pragma unroll
    for (int t = 0; t < T; ++t) { p0[t] = 0.f; p1[t] = 0.f; }

    #pragma unroll
    for (int t = 0; t < T; ++t) {
        #pragma unroll
        for (int j = 0; j < 2; ++j) {
            float4 w = sW4[t * 16 + j * 8 + lane];   // one read, both edges
            #pragma unroll
            for (int k = 0; k < 4; ++k) {
                half2_t wv = __builtin_bit_cast(half2_t, f4_get(w, k));
                p0[t] = dot2acc(h0[j * 4 + k], wv, p0[t]);
                p1[t] = dot2acc(h1[j * 4 + k], wv, p1[t]);
            }
        }
    }

    // 8-lane merge tree: 7 shfls per edge, lane l ends with type l's sum.
    float q0[4], q1[4];
    #pragma unroll
    for (int k = 0; k < 4; ++k) {
        float keep0 = (lane & 1) ? p0[2 * k + 1] : p0[2 * k];
        float send0 = (lane & 1) ? p0[2 * k]     : p0[2 * k + 1];
        q0[k] = keep0 + __shfl_xor(send0, 1);
        float keep1 = (lane & 1) ? p1[2 * k + 1] : p1[2 * k];
        float send1 = (lane & 1) ? p1[2 * k]     : p1[2 * k + 1];
        q1[k] = keep1 + __shfl_xor(send1, 1);
    }
    float r0[2], r1[2];
    #pragma unroll
    for (int k = 0; k < 2; ++k) {
        float keep0 = (lane & 2) ? q0[2 * k + 1] : q0[2 * k];
        float send0 = (lane & 2) ? q0[2 * k]     : q0[2 * k + 1];
        r0[k] = keep0 + __shfl_xor(send0, 2);
        float keep1 = (lane & 2) ? q1[2 * k + 1] : q1[2 * k];
        float send1 = (lane & 2) ? q1[2 * k]     : q1[2 * k + 1];
        r1[k] = keep1 + __shfl_xor(send1, 2);
    }
    const float bias = b[lane];
    {
        float keep = (lane & 4) ? r0[1] : r0[0];
        float send = (lane & 4) ? r0[0] : r0[1];
        float r = keep + __shfl_xor(send, 4) + bias;
        if (v0) __builtin_nontemporal_store(r, &out[(size_t)e0 * T + lane]);
    }
    {
        float keep = (lane & 4) ? r1[1] : r1[0];
        float send = (lane & 4) ? r1[0] : r1[1];
        float r = keep + __shfl_xor(send, 4) + bias;
        if (v1) __builtin_nontemporal_store(r, &out[(size_t)e1 * T + lane]);
    }
}

// ---------------- fallback: round-2 fp32 kernel (if ws too small) ----------------
__device__ __forceinline__ float4 relu_add(float4 a, float4 c) {
    float4 h;
    h.x = fmaxf(a.x + c.x, 0.f);
    h.y = fmaxf(a.y + c.y, 0.f);
    h.z = fmaxf(a.z + c.z, 0.f);
    h.w = fmaxf(a.w + c.w, 0.f);
    return h;
}

__global__ __launch_bounds__(256, 4)
void edge_type_fp32_kernel(const float* __restrict__ x,
                           const int* __restrict__ eidx,
                           const float* __restrict__ W,
                           const float* __restrict__ b,
                           float* __restrict__ out,
                           int E)
{
    __shared__ float sW[T * H];
    for (int i = threadIdx.x; i < T * H; i += blockDim.x) sW[i] = W[i];
    __syncthreads();
    const float4* sW4 = reinterpret_cast<const float4*>(sW);

    const int lane = threadIdx.x & 7;
    const int e    = (blockIdx.x * blockDim.x + threadIdx.x) >> 3;
    if (e >= E) return;

    const int s = eidx[e];
    const int d = eidx[E + e];
    const float4* xs = reinterpret_cast<const float4*>(x) + (size_t)s * H4;
    const float4* xd = reinterpret_cast<const float4*>(x) + (size_t)d * H4;

    float p[T];
    #pragma unroll
    for (int t = 0; t < T; ++t) p[t] = 0.f;

    #pragma unroll
    for (int j = 0; j < 4; ++j) {
        const int o = j * 8 + lane;
        float4 h = relu_add(xs[o], xd[o]);
        #pragma unroll
        for (int t = 0; t < T; ++t) {
            float4 w = sW4[t * H4 + o];
            p[t] = fmaf(h.x, w.x, fmaf(h.y, w.y, fmaf(h.z, w.z, fmaf(h.w, w.w, p[t]))));
        }
    }

    float q[4];
    #pragma unroll
    for (int k = 0; k < 4; ++k) {
        float keep = (lane & 1) ? p[2 * k + 1] : p[2 * k];
        float send = (lane & 1) ? p[2 * k]     : p[2 * k + 1];
        q[k] = keep + __shfl_xor(send, 1);
    }
    float r2[2];
    #pragma unroll
    for (int k = 0; k < 2; ++k) {
        float keep = (lane & 2) ? q[2 * k + 1] : q[2 * k];
        float send = (lane & 2) ? q[2 * k]     : q[2 * k + 1];
        r2[k] = keep + __shfl_xor(send, 2);
    }
    float keep = (lane & 4) ? r2[1] : r2[0];
    float send = (lane & 4) ? r2[0] : r2[1];
    float r = keep + __shfl_xor(send, 4) + b[lane];
    __builtin_nontemporal_store(r, &out[(size_t)e * T + lane]);
}

extern "C" void kernel_launch(void* const* d_in, const int* in_sizes, int n_in,
                              void* d_out, int out_size, void* d_ws, size_t ws_size,
                              hipStream_t stream) {
    const float* x    = (const float*)d_in[0];   // [N_NODES, 128] fp32
    const int*   eidx = (const int*)d_in[1];     // [2, E] int32
    const float* W    = (const float*)d_in[2];   // [8, 128] fp32
    const float* b    = (const float*)d_in[3];   // [8] fp32
    float*       out  = (float*)d_out;           // [E, 8] fp32

    const int E  = in_sizes[1] / 2;
    const int nx = in_sizes[0];                  // node-feature element count

    const size_t need = (size_t)nx * 2;          // fp16 copy of x
    if (ws_size >= need && (nx % 8) == 0) {
        // pre-pass: fp32 -> fp16 (re-run every call; ws is re-poisoned)
        const int n8 = nx / 8;
        cvt_x_kernel<<<dim3((n8 + 255) / 256), dim3(256), 0, stream>>>(
            (const float4*)x, (float4*)d_ws, n8);

        const int blocks = (E + 63) / 64;        // 64 edges per block
        edge_type_fp16_kernel<<<dim3(blocks), dim3(256), 0, stream>>>(
            (const float4*)d_ws, eidx, W, b, out, E);
    } else {
        const int blocks = (E + 31) / 32;        // 32 edges per block
        edge_type_fp32_kernel<<<dim3(blocks), dim3(256), 0, stream>>>(
            x, eidx, W, b, out, E);
    }
}